// Round 6
// baseline (247.720 us; speedup 1.0000x reference)
//
#include <hip/hip_runtime.h>
#include <hip/hip_bf16.h>
#include <hip/hip_cooperative_groups.h>

namespace cg = cooperative_groups;

#define B_   128
#define N_   65536
#define F_   512
#define CS   64                  // samples per chunk (per thread)
#define CPR  (N_ / CS)           // 1024 chunks per row
#define TPB  128                 // threads (=chunks) per block
#define BPR  (CPR / TPB)         // 8 blocks per row
#define NBLK (B_ * BPR)          // 1024 blocks == 4 blocks/CU * 256 CUs (LDS-bound)
#define BLK_SAMP (TPB * CS)      // 8192 samples per block
#define NT   (B_ * CPR)          // 131072 chunks total
#define KPOS ((float)(511.0 / 65535.0))
#define INVK ((float)(65535.0 / 511.0))
#define STRIDE 68                // padded LDS row stride (floats)

// ws layout (floats):
//   pref [6][NT]   : fallback only
//   agg  [NBLK][6] : per-block aggregate transform
#define OFF_PREF 0
#define OFF_AGG  (6 * NT)

__device__ __forceinline__ float tanh_map1(float l) { return 2.0f * tanhf(l); }

// Chunk geometry: I (i0 at chunk start), kc (first sample whose i0 is I+1; CS if
// no crossing), exactly matching reference floorf((n0+k)*K). (verbatim round 5)
__device__ __forceinline__ void chunk_geom(int n0, float& pos0, int& I, int& kc) {
    pos0 = (float)n0 * KPOS;
    I = min((int)pos0, F_ - 2);
    int k = (int)ceilf(((float)(I + 1) - pos0) * INVK);
    k = max(0, min(k, CS));
    if (k > 0 && (int)((float)(n0 + k - 1) * KPOS) > I) --k;
    else if (k < CS && (int)((float)(n0 + k) * KPOS) <= I) ++k;
    if ((int)pos0 > F_ - 2) k = CS;
    if (I == F_ - 2) {
        if ((float)n0 * KPOS >= (float)(F_ - 1)) k = CS;
    }
    kc = k;
}

// ---------------- fused cooperative kernel ----------------
__global__ __launch_bounds__(TPB, 2) void fused(const float* __restrict__ x,
                                                const float* __restrict__ logits,
                                                float* __restrict__ agg,
                                                float* __restrict__ out) {
    __shared__ __align__(16) float buf[TPB][STRIDE];
    __shared__ float sc[6][TPB];
    __shared__ float sbs[2];
    int tid = threadIdx.x;
    int gid = blockIdx.x;
    int gchunk0 = gid * TPB;

    // ---- stage x -> LDS (coalesced float4) ----
    const float4* xg = (const float4*)x + (size_t)gchunk0 * (CS / 4);
    #pragma unroll
    for (int it = 0; it < BLK_SAMP / 4 / TPB; ++it) {
        int i4 = it * TPB + tid;
        float4 v = xg[i4];
        *(float4*)&buf[i4 >> 4][(i4 & 15) * 4] = v;
    }
    __syncthreads();

    int t = gchunk0 + tid;
    int b = t >> 10;
    int c = t & (CPR - 1);
    int n0 = c * CS;

    float pos0; int I, kc;
    chunk_geom(n0, pos0, I, kc);
    int I2 = min(I + 2, F_ - 1);
    const float* Lg = logits + (size_t)b * F_ * 5;
    float a1A = tanh_map1(Lg[I * 5 + 0]);
    float a1B = tanh_map1(Lg[(I + 1) * 5 + 0]);
    float a1C = tanh_map1(Lg[I2 * 5 + 0]);
    float t1A = tanhf(Lg[I * 5 + 1]);
    float t1B = tanhf(Lg[(I + 1) * 5 + 1]);
    float t1C = tanhf(Lg[I2 * 5 + 1]);
    float a2A = 0.5f * ((2.0f - fabsf(a1A)) * t1A + fabsf(a1A));
    float a2B = 0.5f * ((2.0f - fabsf(a1B)) * t1B + fabsf(a1B));
    float a2C = 0.5f * ((2.0f - fabsf(a1C)) * t1C + fabsf(a1C));

    float If = (float)I;
    float C1  = fmaf(pos0 - If,        a1B - a1A, a1A), D1  = KPOS * (a1B - a1A);
    float C1b = fmaf(pos0 - If - 1.f,  a1C - a1B, a1B), D1b = KPOS * (a1C - a1B);
    float C2  = fmaf(pos0 - If,        a2B - a2A, a2A), D2  = KPOS * (a2B - a2A);
    float C2b = fmaf(pos0 - If - 1.f,  a2C - a2B, a2B), D2b = KPOS * (a2C - a2B);

    // ---- compose per-chunk transform (verbatim round 5) ----
    float A00 = 1.f, A01 = 0.f, A10 = 0.f, A11 = 1.f, v0 = 0.f, v1 = 0.f;
    #pragma unroll
    for (int j = 0; j < CS / 4; ++j) {
        float4 xv = *(const float4*)&buf[tid][j * 4];
        #pragma unroll
        for (int u = 0; u < 4; ++u) {
            int k = j * 4 + u;
            float xn = (&xv.x)[u];
            bool sB = (k >= kc);
            float kf = (float)k;
            float a1 = fmaf(kf, sB ? D1b : D1, sB ? C1b : C1);
            float a2 = fmaf(kf, sB ? D2b : D2, sB ? C2b : C2);
            float nA00 = fmaf(-a2, A10, -a1 * A00);
            float nA01 = fmaf(-a2, A11, -a1 * A01);
            float nv0  = fmaf(-a2, v1, fmaf(-a1, v0, xn));
            A10 = A00; A11 = A01; v1 = v0;
            A00 = nA00; A01 = nA01; v0 = nv0;
        }
    }

    // ---- block-local inclusive scan ----
    for (int d = 1; d < TPB; d <<= 1) {
        sc[0][tid] = A00; sc[1][tid] = A01; sc[2][tid] = A10;
        sc[3][tid] = A11; sc[4][tid] = v0;  sc[5][tid] = v1;
        __syncthreads();
        if (tid >= d) {
            float f00 = sc[0][tid - d], f01 = sc[1][tid - d];
            float f10 = sc[2][tid - d], f11 = sc[3][tid - d];
            float fv0 = sc[4][tid - d], fv1 = sc[5][tid - d];
            float n00 = A00 * f00 + A01 * f10;
            float n01 = A00 * f01 + A01 * f11;
            float n10 = A10 * f00 + A11 * f10;
            float n11 = A10 * f01 + A11 * f11;
            float nv0 = A00 * fv0 + A01 * fv1 + v0;
            float nv1 = A10 * fv0 + A11 * fv1 + v1;
            A00 = n00; A01 = n01; A10 = n10; A11 = n11; v0 = nv0; v1 = nv1;
        }
        __syncthreads();
    }
    sc[0][tid] = A00; sc[1][tid] = A01; sc[2][tid] = A10;
    sc[3][tid] = A11; sc[4][tid] = v0;  sc[5][tid] = v1;
    __syncthreads();

    // exclusive block-local prefix -> registers (persist across grid sync)
    float L00, L01, L10, L11, Lv0, Lv1;
    if (tid == 0) { L00 = 1.f; L01 = 0.f; L10 = 0.f; L11 = 1.f; Lv0 = 0.f; Lv1 = 0.f; }
    else {
        L00 = sc[0][tid - 1]; L01 = sc[1][tid - 1];
        L10 = sc[2][tid - 1]; L11 = sc[3][tid - 1];
        Lv0 = sc[4][tid - 1]; Lv1 = sc[5][tid - 1];
    }

    // block aggregate -> global (agent-scope atomics: cross-XCD visible)
    if (tid == TPB - 1) {
        float* T = agg + (size_t)gid * 6;
        __hip_atomic_store(&T[0], A00, __ATOMIC_RELAXED, __HIP_MEMORY_SCOPE_AGENT);
        __hip_atomic_store(&T[1], A01, __ATOMIC_RELAXED, __HIP_MEMORY_SCOPE_AGENT);
        __hip_atomic_store(&T[2], A10, __ATOMIC_RELAXED, __HIP_MEMORY_SCOPE_AGENT);
        __hip_atomic_store(&T[3], A11, __ATOMIC_RELAXED, __HIP_MEMORY_SCOPE_AGENT);
        __hip_atomic_store(&T[4], v0,  __ATOMIC_RELAXED, __HIP_MEMORY_SCOPE_AGENT);
        __hip_atomic_store(&T[5], v1,  __ATOMIC_RELAXED, __HIP_MEMORY_SCOPE_AGENT);
    }
    __threadfence();

    cg::this_grid().sync();

    // ---- fold <=7 predecessor aggregates of this row ----
    int p0 = gid & ~(BPR - 1);
    int np = gid - p0;
    if (tid < np) {
        const float* T = agg + (size_t)(p0 + tid) * 6;
        #pragma unroll
        for (int j = 0; j < 6; ++j)
            sc[j][tid] = __hip_atomic_load(&T[j], __ATOMIC_RELAXED, __HIP_MEMORY_SCOPE_AGENT);
    }
    __syncthreads();
    if (tid == 0) {
        float s0 = 0.f, s1 = 0.f;
        for (int p = 0; p < np; ++p) {
            float n0s = sc[0][p] * s0 + sc[1][p] * s1 + sc[4][p];
            float n1s = sc[2][p] * s0 + sc[3][p] * s1 + sc[5][p];
            s0 = n0s; s1 = n1s;
        }
        sbs[0] = s0; sbs[1] = s1;
    }

    // full 5-coefficient affine params (a-coefs reused from live registers)
    float vA[5], vB[5], vC[5];
    vA[0] = a1A; vB[0] = a1B; vC[0] = a1C;
    vA[1] = a2A; vB[1] = a2B; vC[1] = a2C;
    #pragma unroll
    for (int j = 0; j < 3; ++j) {
        vA[2 + j] = Lg[I * 5 + 2 + j];
        vB[2 + j] = Lg[(I + 1) * 5 + 2 + j];
        vC[2 + j] = Lg[I2 * 5 + 2 + j];
    }
    float Cs[5], Ds[5], Csb[5], Dsb[5];
    #pragma unroll
    for (int j = 0; j < 5; ++j) {
        Cs[j]  = fmaf(pos0 - If,       vB[j] - vA[j], vA[j]);
        Ds[j]  = KPOS * (vB[j] - vA[j]);
        Csb[j] = fmaf(pos0 - If - 1.f, vC[j] - vB[j], vB[j]);
        Dsb[j] = KPOS * (vC[j] - vB[j]);
    }
    __syncthreads();   // sbs ready

    float bs0 = sbs[0], bs1 = sbs[1];
    float s0v = L00 * bs0 + L01 * bs1 + Lv0;   // y[n0-1]
    float s1v = L10 * bs0 + L11 * bs1 + Lv1;   // y[n0-2]

    // ---- recurrence + fused FIR (verbatim round 5) ----
    #pragma unroll
    for (int j = 0; j < CS / 4; ++j) {
        float4 xv = *(const float4*)&buf[tid][j * 4];
        float4 yv;
        #pragma unroll
        for (int u = 0; u < 4; ++u) {
            int k = j * 4 + u;
            float xn = (&xv.x)[u];
            bool sB = (k >= kc);
            float kf = (float)k;
            float a1 = fmaf(kf, sB ? Dsb[0] : Ds[0], sB ? Csb[0] : Cs[0]);
            float a2 = fmaf(kf, sB ? Dsb[1] : Ds[1], sB ? Csb[1] : Cs[1]);
            float b0 = fmaf(kf, sB ? Dsb[2] : Ds[2], sB ? Csb[2] : Cs[2]);
            float b1 = fmaf(kf, sB ? Dsb[3] : Ds[3], sB ? Csb[3] : Cs[3]);
            float b2 = fmaf(kf, sB ? Dsb[4] : Ds[4], sB ? Csb[4] : Cs[4]);
            float y = fmaf(-a2, s1v, fmaf(-a1, s0v, xn));
            (&yv.x)[u] = fmaf(b2, s1v, fmaf(b1, s0v, b0 * y));
            s1v = s0v; s0v = y;
        }
        *(float4*)&buf[tid][j * 4] = yv;
    }
    __syncthreads();

    float4* og = (float4*)out + (size_t)gchunk0 * (CS / 4);
    #pragma unroll
    for (int it = 0; it < BLK_SAMP / 4 / TPB; ++it) {
        int i4 = it * TPB + tid;
        og[i4] = *(float4*)&buf[i4 >> 4][(i4 & 15) * 4];
    }
}

// ---------------- fallback path (verbatim round 5) ----------------
__global__ __launch_bounds__(TPB, 2) void phaseA(const float* __restrict__ x,
                                                 const float* __restrict__ logits,
                                                 float* __restrict__ pref,
                                                 float* __restrict__ agg) {
    __shared__ __align__(16) float buf[TPB][STRIDE];
    __shared__ float sc[6][TPB];
    int tid = threadIdx.x;
    int gid = blockIdx.x;
    int gchunk0 = gid * TPB;

    const float4* xg = (const float4*)x + (size_t)gchunk0 * (CS / 4);
    #pragma unroll
    for (int it = 0; it < BLK_SAMP / 4 / TPB; ++it) {
        int i4 = it * TPB + tid;
        float4 v = xg[i4];
        *(float4*)&buf[i4 >> 4][(i4 & 15) * 4] = v;
    }
    __syncthreads();

    int t = gchunk0 + tid;
    int b = t >> 10;
    int c = t & (CPR - 1);
    int n0 = c * CS;

    float pos0; int I, kc;
    chunk_geom(n0, pos0, I, kc);
    int I2 = min(I + 2, F_ - 1);
    const float* Lg = logits + (size_t)b * F_ * 5;
    float a1A = tanh_map1(Lg[I * 5 + 0]);
    float a1B = tanh_map1(Lg[(I + 1) * 5 + 0]);
    float a1C = tanh_map1(Lg[I2 * 5 + 0]);
    float t1A = tanhf(Lg[I * 5 + 1]);
    float t1B = tanhf(Lg[(I + 1) * 5 + 1]);
    float t1C = tanhf(Lg[I2 * 5 + 1]);
    float a2A = 0.5f * ((2.0f - fabsf(a1A)) * t1A + fabsf(a1A));
    float a2B = 0.5f * ((2.0f - fabsf(a1B)) * t1B + fabsf(a1B));
    float a2C = 0.5f * ((2.0f - fabsf(a1C)) * t1C + fabsf(a1C));

    float If = (float)I;
    float C1  = fmaf(pos0 - If,        a1B - a1A, a1A), D1  = KPOS * (a1B - a1A);
    float C1b = fmaf(pos0 - If - 1.f,  a1C - a1B, a1B), D1b = KPOS * (a1C - a1B);
    float C2  = fmaf(pos0 - If,        a2B - a2A, a2A), D2  = KPOS * (a2B - a2A);
    float C2b = fmaf(pos0 - If - 1.f,  a2C - a2B, a2B), D2b = KPOS * (a2C - a2B);

    float A00 = 1.f, A01 = 0.f, A10 = 0.f, A11 = 1.f, v0 = 0.f, v1 = 0.f;
    #pragma unroll
    for (int j = 0; j < CS / 4; ++j) {
        float4 xv = *(const float4*)&buf[tid][j * 4];
        #pragma unroll
        for (int u = 0; u < 4; ++u) {
            int k = j * 4 + u;
            float xn = (&xv.x)[u];
            bool sB = (k >= kc);
            float kf = (float)k;
            float a1 = fmaf(kf, sB ? D1b : D1, sB ? C1b : C1);
            float a2 = fmaf(kf, sB ? D2b : D2, sB ? C2b : C2);
            float nA00 = fmaf(-a2, A10, -a1 * A00);
            float nA01 = fmaf(-a2, A11, -a1 * A01);
            float nv0  = fmaf(-a2, v1, fmaf(-a1, v0, xn));
            A10 = A00; A11 = A01; v1 = v0;
            A00 = nA00; A01 = nA01; v0 = nv0;
        }
    }

    for (int d = 1; d < TPB; d <<= 1) {
        sc[0][tid] = A00; sc[1][tid] = A01; sc[2][tid] = A10;
        sc[3][tid] = A11; sc[4][tid] = v0;  sc[5][tid] = v1;
        __syncthreads();
        if (tid >= d) {
            float f00 = sc[0][tid - d], f01 = sc[1][tid - d];
            float f10 = sc[2][tid - d], f11 = sc[3][tid - d];
            float fv0 = sc[4][tid - d], fv1 = sc[5][tid - d];
            float n00 = A00 * f00 + A01 * f10;
            float n01 = A00 * f01 + A01 * f11;
            float n10 = A10 * f00 + A11 * f10;
            float n11 = A10 * f01 + A11 * f11;
            float nv0 = A00 * fv0 + A01 * fv1 + v0;
            float nv1 = A10 * fv0 + A11 * fv1 + v1;
            A00 = n00; A01 = n01; A10 = n10; A11 = n11; v0 = nv0; v1 = nv1;
        }
        __syncthreads();
    }
    sc[0][tid] = A00; sc[1][tid] = A01; sc[2][tid] = A10;
    sc[3][tid] = A11; sc[4][tid] = v0;  sc[5][tid] = v1;
    __syncthreads();

    float e00, e01, e10, e11, ev0, ev1;
    if (tid == 0) { e00 = 1.f; e01 = 0.f; e10 = 0.f; e11 = 1.f; ev0 = 0.f; ev1 = 0.f; }
    else {
        e00 = sc[0][tid - 1]; e01 = sc[1][tid - 1];
        e10 = sc[2][tid - 1]; e11 = sc[3][tid - 1];
        ev0 = sc[4][tid - 1]; ev1 = sc[5][tid - 1];
    }
    pref[0 * NT + t] = e00; pref[1 * NT + t] = e01;
    pref[2 * NT + t] = e10; pref[3 * NT + t] = e11;
    pref[4 * NT + t] = ev0; pref[5 * NT + t] = ev1;
    if (tid == TPB - 1) {
        float* T = agg + (size_t)gid * 6;
        T[0] = A00; T[1] = A01; T[2] = A10; T[3] = A11; T[4] = v0; T[5] = v1;
    }
}

__global__ __launch_bounds__(TPB, 2) void phaseC(const float* __restrict__ x,
                                                 const float* __restrict__ logits,
                                                 const float* __restrict__ pref,
                                                 const float* __restrict__ agg,
                                                 float* __restrict__ out) {
    __shared__ __align__(16) float buf[TPB][STRIDE];
    __shared__ float sbs[2];
    int tid = threadIdx.x;
    int gid = blockIdx.x;
    int gchunk0 = gid * TPB;

    const float4* xg = (const float4*)x + (size_t)gchunk0 * (CS / 4);
    #pragma unroll
    for (int it = 0; it < BLK_SAMP / 4 / TPB; ++it) {
        int i4 = it * TPB + tid;
        float4 v = xg[i4];
        *(float4*)&buf[i4 >> 4][(i4 & 15) * 4] = v;
    }

    if (tid == 0) {
        float s0 = 0.f, s1 = 0.f;
        int p0 = gid & ~(BPR - 1);
        for (int p = p0; p < gid; ++p) {
            const float* T = agg + (size_t)p * 6;
            float n0s = T[0] * s0 + T[1] * s1 + T[4];
            float n1s = T[2] * s0 + T[3] * s1 + T[5];
            s0 = n0s; s1 = n1s;
        }
        sbs[0] = s0; sbs[1] = s1;
    }

    int t = gchunk0 + tid;
    int b = t >> 10;
    int c = t & (CPR - 1);
    int n0 = c * CS;

    float pos0; int I, kc;
    chunk_geom(n0, pos0, I, kc);
    int I2 = min(I + 2, F_ - 1);
    const float* Lg = logits + (size_t)b * F_ * 5;
    float vA[5], vB[5], vC[5];
    {
        float a1A = tanh_map1(Lg[I * 5 + 0]);
        float a1B = tanh_map1(Lg[(I + 1) * 5 + 0]);
        float a1C = tanh_map1(Lg[I2 * 5 + 0]);
        float t1A = tanhf(Lg[I * 5 + 1]);
        float t1B = tanhf(Lg[(I + 1) * 5 + 1]);
        float t1C = tanhf(Lg[I2 * 5 + 1]);
        vA[0] = a1A; vB[0] = a1B; vC[0] = a1C;
        vA[1] = 0.5f * ((2.0f - fabsf(a1A)) * t1A + fabsf(a1A));
        vB[1] = 0.5f * ((2.0f - fabsf(a1B)) * t1B + fabsf(a1B));
        vC[1] = 0.5f * ((2.0f - fabsf(a1C)) * t1C + fabsf(a1C));
        #pragma unroll
        for (int j = 0; j < 3; ++j) {
            vA[2 + j] = Lg[I * 5 + 2 + j];
            vB[2 + j] = Lg[(I + 1) * 5 + 2 + j];
            vC[2 + j] = Lg[I2 * 5 + 2 + j];
        }
    }
    float If = (float)I;
    float Cs[5], Ds[5], Csb[5], Dsb[5];
    #pragma unroll
    for (int j = 0; j < 5; ++j) {
        Cs[j]  = fmaf(pos0 - If,       vB[j] - vA[j], vA[j]);
        Ds[j]  = KPOS * (vB[j] - vA[j]);
        Csb[j] = fmaf(pos0 - If - 1.f, vC[j] - vB[j], vB[j]);
        Dsb[j] = KPOS * (vC[j] - vB[j]);
    }

    float L00 = pref[0 * NT + t], L01 = pref[1 * NT + t];
    float L10 = pref[2 * NT + t], L11 = pref[3 * NT + t];
    float Lv0 = pref[4 * NT + t], Lv1 = pref[5 * NT + t];

    __syncthreads();

    float bs0 = sbs[0], bs1 = sbs[1];
    float s0v = L00 * bs0 + L01 * bs1 + Lv0;
    float s1v = L10 * bs0 + L11 * bs1 + Lv1;

    #pragma unroll
    for (int j = 0; j < CS / 4; ++j) {
        float4 xv = *(const float4*)&buf[tid][j * 4];
        float4 yv;
        #pragma unroll
        for (int u = 0; u < 4; ++u) {
            int k = j * 4 + u;
            float xn = (&xv.x)[u];
            bool sB = (k >= kc);
            float kf = (float)k;
            float a1 = fmaf(kf, sB ? Dsb[0] : Ds[0], sB ? Csb[0] : Cs[0]);
            float a2 = fmaf(kf, sB ? Dsb[1] : Ds[1], sB ? Csb[1] : Cs[1]);
            float b0 = fmaf(kf, sB ? Dsb[2] : Ds[2], sB ? Csb[2] : Cs[2]);
            float b1 = fmaf(kf, sB ? Dsb[3] : Ds[3], sB ? Csb[3] : Cs[3]);
            float b2 = fmaf(kf, sB ? Dsb[4] : Ds[4], sB ? Csb[4] : Cs[4]);
            float y = fmaf(-a2, s1v, fmaf(-a1, s0v, xn));
            (&yv.x)[u] = fmaf(b2, s1v, fmaf(b1, s0v, b0 * y));
            s1v = s0v; s0v = y;
        }
        *(float4*)&buf[tid][j * 4] = yv;
    }
    __syncthreads();

    float4* og = (float4*)out + (size_t)gchunk0 * (CS / 4);
    #pragma unroll
    for (int it = 0; it < BLK_SAMP / 4 / TPB; ++it) {
        int i4 = it * TPB + tid;
        og[i4] = *(float4*)&buf[i4 >> 4][(i4 & 15) * 4];
    }
}

extern "C" void kernel_launch(void* const* d_in, const int* in_sizes, int n_in,
                              void* d_out, int out_size, void* d_ws, size_t ws_size,
                              hipStream_t stream) {
    const float* x      = (const float*)d_in[0];   // (B, N) f32
    const float* logits = (const float*)d_in[1];   // (B, F, 5) f32
    float* out = (float*)d_out;                    // (B, N) f32
    float* ws  = (float*)d_ws;

    float* pref = ws + OFF_PREF;
    float* agg  = ws + OFF_AGG;

    const float* xa = x; const float* la = logits; float* aa = agg; float* oa = out;
    void* args[] = { (void*)&xa, (void*)&la, (void*)&aa, (void*)&oa };
    hipError_t err = hipLaunchCooperativeKernel((void*)fused, dim3(NBLK), dim3(TPB),
                                                args, 0, stream);
    if (err != hipSuccess) {
        // deterministic fallback: round-5 two-kernel path
        phaseA<<<NBLK, TPB, 0, stream>>>(x, logits, pref, agg);
        phaseC<<<NBLK, TPB, 0, stream>>>(x, logits, pref, agg, out);
    }
}

// Round 7
// 116.845 us; speedup vs baseline: 2.1201x; 2.1201x over previous
//
#include <hip/hip_runtime.h>
#include <hip/hip_bf16.h>

#define B_   128
#define N_   65536
#define F_   512
#define CS   64                  // samples per chunk (per thread)
#define CPR  (N_ / CS)           // 1024 chunks per row
#define TPB  128                 // threads (=chunks) per block
#define BPR  (CPR / TPB)         // 8 blocks per row
#define NBLK (B_ * BPR)          // 1024 blocks == 4 blocks/CU * 256 CU (all co-resident)
#define BLK_SAMP (TPB * CS)      // 8192 samples per block
#define KPOS ((float)(511.0 / 65535.0))
#define INVK ((float)(65535.0 / 511.0))
#define STRIDE 68                // padded LDS row stride (floats)
#define MAGIC 0x5A17F00Du        // publish flag; ws poison 0xAAAAAAAA != MAGIC

__device__ __forceinline__ float tanh_map1(float l) { return 2.0f * tanhf(l); }

// Chunk geometry: I (i0 at chunk start), kc (first sample whose i0 is I+1; CS if
// no crossing), exactly matching reference floorf((n0+k)*K).
__device__ __forceinline__ void chunk_geom(int n0, float& pos0, int& I, int& kc) {
    pos0 = (float)n0 * KPOS;
    I = min((int)pos0, F_ - 2);
    int k = (int)ceilf(((float)(I + 1) - pos0) * INVK);
    k = max(0, min(k, CS));
    if (k > 0 && (int)((float)(n0 + k - 1) * KPOS) > I) --k;
    else if (k < CS && (int)((float)(n0 + k) * KPOS) <= I) ++k;
    if ((int)pos0 > F_ - 2) k = CS;
    if (I == F_ - 2) {
        if ((float)n0 * KPOS >= (float)(F_ - 1)) k = CS;
    }
    kc = k;
}

// Single fused kernel: compose + block scan + decoupled lookback (<=7 preds in
// row) + recurrence + fused FIR. One pass over x (stays in LDS throughout).
__global__ __launch_bounds__(TPB, 2) void fused_lb(const float* __restrict__ x,
                                                   const float* __restrict__ logits,
                                                   float* __restrict__ agg,
                                                   unsigned int* __restrict__ flags,
                                                   float* __restrict__ out) {
    __shared__ __align__(16) float buf[TPB][STRIDE];
    __shared__ float sc[6][TPB];
    __shared__ float sbs[2];
    int tid = threadIdx.x;
    int gid = blockIdx.x;
    int gchunk0 = gid * TPB;

    // ---- stage x -> LDS (coalesced float4), the ONLY global read of x ----
    const float4* xg = (const float4*)x + (size_t)gchunk0 * (CS / 4);
    #pragma unroll
    for (int it = 0; it < BLK_SAMP / 4 / TPB; ++it) {
        int i4 = it * TPB + tid;
        float4 v = xg[i4];
        *(float4*)&buf[i4 >> 4][(i4 & 15) * 4] = v;
    }
    __syncthreads();

    int t = gchunk0 + tid;
    int b = t >> 10;
    int c = t & (CPR - 1);
    int n0 = c * CS;

    float pos0; int I, kc;
    chunk_geom(n0, pos0, I, kc);
    int I2 = min(I + 2, F_ - 1);
    const float* Lg = logits + (size_t)b * F_ * 5;
    float a1A = tanh_map1(Lg[I * 5 + 0]);
    float a1B = tanh_map1(Lg[(I + 1) * 5 + 0]);
    float a1C = tanh_map1(Lg[I2 * 5 + 0]);
    float t1A = tanhf(Lg[I * 5 + 1]);
    float t1B = tanhf(Lg[(I + 1) * 5 + 1]);
    float t1C = tanhf(Lg[I2 * 5 + 1]);
    float a2A = 0.5f * ((2.0f - fabsf(a1A)) * t1A + fabsf(a1A));
    float a2B = 0.5f * ((2.0f - fabsf(a1B)) * t1B + fabsf(a1B));
    float a2C = 0.5f * ((2.0f - fabsf(a1C)) * t1C + fabsf(a1C));

    float If = (float)I;
    float C1  = fmaf(pos0 - If,        a1B - a1A, a1A), D1  = KPOS * (a1B - a1A);
    float C1b = fmaf(pos0 - If - 1.f,  a1C - a1B, a1B), D1b = KPOS * (a1C - a1B);
    float C2  = fmaf(pos0 - If,        a2B - a2A, a2A), D2  = KPOS * (a2B - a2A);
    float C2b = fmaf(pos0 - If - 1.f,  a2C - a2B, a2B), D2b = KPOS * (a2C - a2B);

    // ---- compose per-chunk affine transform ----
    float A00 = 1.f, A01 = 0.f, A10 = 0.f, A11 = 1.f, v0 = 0.f, v1 = 0.f;
    #pragma unroll
    for (int j = 0; j < CS / 4; ++j) {
        float4 xv = *(const float4*)&buf[tid][j * 4];
        #pragma unroll
        for (int u = 0; u < 4; ++u) {
            int k = j * 4 + u;
            float xn = (&xv.x)[u];
            bool sB = (k >= kc);
            float kf = (float)k;
            float a1 = fmaf(kf, sB ? D1b : D1, sB ? C1b : C1);
            float a2 = fmaf(kf, sB ? D2b : D2, sB ? C2b : C2);
            float nA00 = fmaf(-a2, A10, -a1 * A00);
            float nA01 = fmaf(-a2, A11, -a1 * A01);
            float nv0  = fmaf(-a2, v1, fmaf(-a1, v0, xn));
            A10 = A00; A11 = A01; v1 = v0;
            A00 = nA00; A01 = nA01; v0 = nv0;
        }
    }

    // ---- block-local inclusive scan ----
    for (int d = 1; d < TPB; d <<= 1) {
        sc[0][tid] = A00; sc[1][tid] = A01; sc[2][tid] = A10;
        sc[3][tid] = A11; sc[4][tid] = v0;  sc[5][tid] = v1;
        __syncthreads();
        if (tid >= d) {
            float f00 = sc[0][tid - d], f01 = sc[1][tid - d];
            float f10 = sc[2][tid - d], f11 = sc[3][tid - d];
            float fv0 = sc[4][tid - d], fv1 = sc[5][tid - d];
            float n00 = A00 * f00 + A01 * f10;
            float n01 = A00 * f01 + A01 * f11;
            float n10 = A10 * f00 + A11 * f10;
            float n11 = A10 * f01 + A11 * f11;
            float nv0 = A00 * fv0 + A01 * fv1 + v0;
            float nv1 = A10 * fv0 + A11 * fv1 + v1;
            A00 = n00; A01 = n01; A10 = n10; A11 = n11; v0 = nv0; v1 = nv1;
        }
        __syncthreads();
    }
    sc[0][tid] = A00; sc[1][tid] = A01; sc[2][tid] = A10;
    sc[3][tid] = A11; sc[4][tid] = v0;  sc[5][tid] = v1;
    __syncthreads();

    // exclusive block-local prefix -> registers
    float L00, L01, L10, L11, Lv0, Lv1;
    if (tid == 0) { L00 = 1.f; L01 = 0.f; L10 = 0.f; L11 = 1.f; Lv0 = 0.f; Lv1 = 0.f; }
    else {
        L00 = sc[0][tid - 1]; L01 = sc[1][tid - 1];
        L10 = sc[2][tid - 1]; L11 = sc[3][tid - 1];
        Lv0 = sc[4][tid - 1]; Lv1 = sc[5][tid - 1];
    }
    __syncthreads();   // everyone done reading sc before lookback reuses it

    // ---- publish this block's aggregate (release-agent flag) ----
    if (tid == TPB - 1) {
        float* T = agg + (size_t)gid * 6;
        __hip_atomic_store(&T[0], A00, __ATOMIC_RELAXED, __HIP_MEMORY_SCOPE_AGENT);
        __hip_atomic_store(&T[1], A01, __ATOMIC_RELAXED, __HIP_MEMORY_SCOPE_AGENT);
        __hip_atomic_store(&T[2], A10, __ATOMIC_RELAXED, __HIP_MEMORY_SCOPE_AGENT);
        __hip_atomic_store(&T[3], A11, __ATOMIC_RELAXED, __HIP_MEMORY_SCOPE_AGENT);
        __hip_atomic_store(&T[4], v0,  __ATOMIC_RELAXED, __HIP_MEMORY_SCOPE_AGENT);
        __hip_atomic_store(&T[5], v1,  __ATOMIC_RELAXED, __HIP_MEMORY_SCOPE_AGENT);
        __hip_atomic_store(&flags[gid], MAGIC, __ATOMIC_RELEASE, __HIP_MEMORY_SCOPE_AGENT);
    }

    // ---- decoupled lookback: wait for the <=7 row-predecessors' aggregates ----
    int p0 = gid & ~(BPR - 1);
    int np = gid - p0;
    if (tid < np) {
        int p = p0 + tid;
        while (__hip_atomic_load(&flags[p], __ATOMIC_ACQUIRE, __HIP_MEMORY_SCOPE_AGENT)
               != MAGIC) {
            __builtin_amdgcn_s_sleep(1);
        }
        const float* T = agg + (size_t)p * 6;
        #pragma unroll
        for (int j = 0; j < 6; ++j)
            sc[j][tid] = __hip_atomic_load(&T[j], __ATOMIC_RELAXED, __HIP_MEMORY_SCOPE_AGENT);
    }
    __syncthreads();
    if (tid == 0) {
        float s0 = 0.f, s1 = 0.f;
        for (int p = 0; p < np; ++p) {
            float n0s = sc[0][p] * s0 + sc[1][p] * s1 + sc[4][p];
            float n1s = sc[2][p] * s0 + sc[3][p] * s1 + sc[5][p];
            s0 = n0s; s1 = n1s;
        }
        sbs[0] = s0; sbs[1] = s1;
    }

    // full 5-coefficient affine params (a-coefs reused from live registers)
    float vA[5], vB[5], vC[5];
    vA[0] = a1A; vB[0] = a1B; vC[0] = a1C;
    vA[1] = a2A; vB[1] = a2B; vC[1] = a2C;
    #pragma unroll
    for (int j = 0; j < 3; ++j) {
        vA[2 + j] = Lg[I * 5 + 2 + j];
        vB[2 + j] = Lg[(I + 1) * 5 + 2 + j];
        vC[2 + j] = Lg[I2 * 5 + 2 + j];
    }
    float Cs[5], Ds[5], Csb[5], Dsb[5];
    #pragma unroll
    for (int j = 0; j < 5; ++j) {
        Cs[j]  = fmaf(pos0 - If,       vB[j] - vA[j], vA[j]);
        Ds[j]  = KPOS * (vB[j] - vA[j]);
        Csb[j] = fmaf(pos0 - If - 1.f, vC[j] - vB[j], vB[j]);
        Dsb[j] = KPOS * (vC[j] - vB[j]);
    }
    __syncthreads();   // sbs ready

    float bs0 = sbs[0], bs1 = sbs[1];
    float s0v = L00 * bs0 + L01 * bs1 + Lv0;   // y[n0-1]
    float s1v = L10 * bs0 + L11 * bs1 + Lv1;   // y[n0-2]

    // ---- recurrence + fused FIR (x still live in LDS) ----
    #pragma unroll
    for (int j = 0; j < CS / 4; ++j) {
        float4 xv = *(const float4*)&buf[tid][j * 4];
        float4 yv;
        #pragma unroll
        for (int u = 0; u < 4; ++u) {
            int k = j * 4 + u;
            float xn = (&xv.x)[u];
            bool sB = (k >= kc);
            float kf = (float)k;
            float a1 = fmaf(kf, sB ? Dsb[0] : Ds[0], sB ? Csb[0] : Cs[0]);
            float a2 = fmaf(kf, sB ? Dsb[1] : Ds[1], sB ? Csb[1] : Cs[1]);
            float b0 = fmaf(kf, sB ? Dsb[2] : Ds[2], sB ? Csb[2] : Cs[2]);
            float b1 = fmaf(kf, sB ? Dsb[3] : Ds[3], sB ? Csb[3] : Cs[3]);
            float b2 = fmaf(kf, sB ? Dsb[4] : Ds[4], sB ? Csb[4] : Cs[4]);
            float y = fmaf(-a2, s1v, fmaf(-a1, s0v, xn));
            (&yv.x)[u] = fmaf(b2, s1v, fmaf(b1, s0v, b0 * y));
            s1v = s0v; s0v = y;
        }
        *(float4*)&buf[tid][j * 4] = yv;
    }
    __syncthreads();

    float4* og = (float4*)out + (size_t)gchunk0 * (CS / 4);
    #pragma unroll
    for (int it = 0; it < BLK_SAMP / 4 / TPB; ++it) {
        int i4 = it * TPB + tid;
        og[i4] = *(float4*)&buf[i4 >> 4][(i4 & 15) * 4];
    }
}

extern "C" void kernel_launch(void* const* d_in, const int* in_sizes, int n_in,
                              void* d_out, int out_size, void* d_ws, size_t ws_size,
                              hipStream_t stream) {
    const float* x      = (const float*)d_in[0];   // (B, N) f32
    const float* logits = (const float*)d_in[1];   // (B, F, 5) f32
    float* out = (float*)d_out;                    // (B, N) f32
    float* ws  = (float*)d_ws;

    float* agg = ws;                                    // [NBLK][6] floats
    unsigned int* flags = (unsigned int*)(ws + 6 * NBLK);  // [NBLK] u32 (poisoned 0xAA.. each replay)

    fused_lb<<<NBLK, TPB, 0, stream>>>(x, logits, agg, flags, out);
}

// Round 8
// 105.531 us; speedup vs baseline: 2.3474x; 1.1072x over previous
//
#include <hip/hip_runtime.h>
#include <hip/hip_bf16.h>

#define B_   128
#define N_   65536
#define F_   512
#define CS   16                  // samples per chunk (per thread)
#define CPR  (N_ / CS)           // 4096 chunks per row
#define TPB  512                 // threads (=chunks) per block -> 8192 samples/block
#define BPR  (CPR / TPB)         // 8 blocks per row
#define NBLK (B_ * BPR)          // 1024 blocks
#define NCH  (B_ * CPR)          // 524288 chunks total
#define KPOS ((float)(511.0 / 65535.0))
#define INVK ((float)(65535.0 / 511.0))

// ws layout (floats):
//   pref [6][NCH]  : per-chunk exclusive block-local prefix (SoA, coalesced) ~12.6 MB
//   agg  [NBLK][6] : per-block aggregate transform
#define OFF_PREF 0
#define OFF_AGG  (6 * NCH)

__device__ __forceinline__ float tanh_map1(float l) { return 2.0f * tanhf(l); }

// Chunk geometry: I (i0 at chunk start), kc (first sample whose i0 is I+1; CS if
// no crossing), exactly matching reference floorf((n0+k)*K).
__device__ __forceinline__ void chunk_geom(int n0, float& pos0, int& I, int& kc) {
    pos0 = (float)n0 * KPOS;
    I = min((int)pos0, F_ - 2);
    int k = (int)ceilf(((float)(I + 1) - pos0) * INVK);
    k = max(0, min(k, CS));
    if (k > 0 && (int)((float)(n0 + k - 1) * KPOS) > I) --k;
    else if (k < CS && (int)((float)(n0 + k) * KPOS) <= I) ++k;
    if ((int)pos0 > F_ - 2) k = CS;
    if (I == F_ - 2) {
        if ((float)n0 * KPOS >= (float)(F_ - 1)) k = CS;
    }
    kc = k;
}

// Kernel A: per-thread direct x reads (64 B contiguous), compose 16-sample
// transform, block-wide scan (depth 9), persist exclusive prefixes + block agg.
__global__ __launch_bounds__(TPB, 4) void phaseA(const float* __restrict__ x,
                                                 const float* __restrict__ logits,
                                                 float* __restrict__ pref,
                                                 float* __restrict__ agg) {
    __shared__ float sc[6][TPB];
    int tid = threadIdx.x;
    int gid = blockIdx.x;
    int t = gid * TPB + tid;         // global 16-chunk id
    int c = t & (CPR - 1);
    int n0 = c * CS;

    float pos0; int I, kc;
    chunk_geom(n0, pos0, I, kc);
    int I2 = min(I + 2, F_ - 1);
    const float* Lg = logits + (size_t)(t >> 12) * F_ * 5;
    float a1A = tanh_map1(Lg[I * 5 + 0]);
    float a1B = tanh_map1(Lg[(I + 1) * 5 + 0]);
    float a1C = tanh_map1(Lg[I2 * 5 + 0]);
    float t1A = tanhf(Lg[I * 5 + 1]);
    float t1B = tanhf(Lg[(I + 1) * 5 + 1]);
    float t1C = tanhf(Lg[I2 * 5 + 1]);
    float a2A = 0.5f * ((2.0f - fabsf(a1A)) * t1A + fabsf(a1A));
    float a2B = 0.5f * ((2.0f - fabsf(a1B)) * t1B + fabsf(a1B));
    float a2C = 0.5f * ((2.0f - fabsf(a1C)) * t1C + fabsf(a1C));

    float If = (float)I;
    float C1  = fmaf(pos0 - If,        a1B - a1A, a1A), D1  = KPOS * (a1B - a1A);
    float C1b = fmaf(pos0 - If - 1.f,  a1C - a1B, a1B), D1b = KPOS * (a1C - a1B);
    float C2  = fmaf(pos0 - If,        a2B - a2A, a2A), D2  = KPOS * (a2B - a2A);
    float C2b = fmaf(pos0 - If - 1.f,  a2C - a2B, a2B), D2b = KPOS * (a2C - a2B);

    // ---- compose this chunk's affine transform (direct global reads) ----
    const float4* xp = (const float4*)x + (size_t)t * (CS / 4);
    float A00 = 1.f, A01 = 0.f, A10 = 0.f, A11 = 1.f, v0 = 0.f, v1 = 0.f;
    #pragma unroll
    for (int j = 0; j < CS / 4; ++j) {
        float4 xv = xp[j];
        #pragma unroll
        for (int u = 0; u < 4; ++u) {
            int k = j * 4 + u;
            float xn = (&xv.x)[u];
            bool sB = (k >= kc);
            float kf = (float)k;
            float a1 = fmaf(kf, sB ? D1b : D1, sB ? C1b : C1);
            float a2 = fmaf(kf, sB ? D2b : D2, sB ? C2b : C2);
            float nA00 = fmaf(-a2, A10, -a1 * A00);
            float nA01 = fmaf(-a2, A11, -a1 * A01);
            float nv0  = fmaf(-a2, v1, fmaf(-a1, v0, xn));
            A10 = A00; A11 = A01; v1 = v0;
            A00 = nA00; A01 = nA01; v0 = nv0;
        }
    }

    // ---- block-wide inclusive Hillis-Steele scan over TPB transforms ----
    for (int d = 1; d < TPB; d <<= 1) {
        sc[0][tid] = A00; sc[1][tid] = A01; sc[2][tid] = A10;
        sc[3][tid] = A11; sc[4][tid] = v0;  sc[5][tid] = v1;
        __syncthreads();
        if (tid >= d) {
            float f00 = sc[0][tid - d], f01 = sc[1][tid - d];
            float f10 = sc[2][tid - d], f11 = sc[3][tid - d];
            float fv0 = sc[4][tid - d], fv1 = sc[5][tid - d];
            float n00 = A00 * f00 + A01 * f10;
            float n01 = A00 * f01 + A01 * f11;
            float n10 = A10 * f00 + A11 * f10;
            float n11 = A10 * f01 + A11 * f11;
            float nv0 = A00 * fv0 + A01 * fv1 + v0;
            float nv1 = A10 * fv0 + A11 * fv1 + v1;
            A00 = n00; A01 = n01; A10 = n10; A11 = n11; v0 = nv0; v1 = nv1;
        }
        __syncthreads();
    }
    sc[0][tid] = A00; sc[1][tid] = A01; sc[2][tid] = A10;
    sc[3][tid] = A11; sc[4][tid] = v0;  sc[5][tid] = v1;
    __syncthreads();

    float e00, e01, e10, e11, ev0, ev1;
    if (tid == 0) { e00 = 1.f; e01 = 0.f; e10 = 0.f; e11 = 1.f; ev0 = 0.f; ev1 = 0.f; }
    else {
        e00 = sc[0][tid - 1]; e01 = sc[1][tid - 1];
        e10 = sc[2][tid - 1]; e11 = sc[3][tid - 1];
        ev0 = sc[4][tid - 1]; ev1 = sc[5][tid - 1];
    }
    pref[0 * NCH + t] = e00; pref[1 * NCH + t] = e01;
    pref[2 * NCH + t] = e10; pref[3 * NCH + t] = e11;
    pref[4 * NCH + t] = ev0; pref[5 * NCH + t] = ev1;
    if (tid == TPB - 1) {
        float* T = agg + (size_t)gid * 6;
        T[0] = A00; T[1] = A01; T[2] = A10; T[3] = A11; T[4] = v0; T[5] = v1;
    }
}

// Kernel C: fold <=7 row-predecessor aggregates, apply per-chunk prefix,
// run 16-sample recurrence + fused FIR, write 64 B contiguous per thread.
__global__ __launch_bounds__(TPB, 4) void phaseC(const float* __restrict__ x,
                                                 const float* __restrict__ logits,
                                                 const float* __restrict__ pref,
                                                 const float* __restrict__ agg,
                                                 float* __restrict__ out) {
    __shared__ float sAgg[8][6];
    __shared__ float sbs[2];
    int tid = threadIdx.x;
    int gid = blockIdx.x;
    int t = gid * TPB + tid;
    int c = t & (CPR - 1);
    int n0 = c * CS;

    int p0 = gid & ~(BPR - 1);
    int np = gid - p0;
    if (tid < np) {
        const float* T = agg + (size_t)(p0 + tid) * 6;
        #pragma unroll
        for (int j = 0; j < 6; ++j) sAgg[tid][j] = T[j];
    }
    __syncthreads();
    if (tid == 0) {
        float s0 = 0.f, s1 = 0.f;
        for (int p = 0; p < np; ++p) {
            float n0s = sAgg[p][0] * s0 + sAgg[p][1] * s1 + sAgg[p][4];
            float n1s = sAgg[p][2] * s0 + sAgg[p][3] * s1 + sAgg[p][5];
            s0 = n0s; s1 = n1s;
        }
        sbs[0] = s0; sbs[1] = s1;
    }

    float pos0; int I, kc;
    chunk_geom(n0, pos0, I, kc);
    int I2 = min(I + 2, F_ - 1);
    const float* Lg = logits + (size_t)(t >> 12) * F_ * 5;
    float vA[5], vB[5], vC[5];
    {
        float a1A = tanh_map1(Lg[I * 5 + 0]);
        float a1B = tanh_map1(Lg[(I + 1) * 5 + 0]);
        float a1C = tanh_map1(Lg[I2 * 5 + 0]);
        float t1A = tanhf(Lg[I * 5 + 1]);
        float t1B = tanhf(Lg[(I + 1) * 5 + 1]);
        float t1C = tanhf(Lg[I2 * 5 + 1]);
        vA[0] = a1A; vB[0] = a1B; vC[0] = a1C;
        vA[1] = 0.5f * ((2.0f - fabsf(a1A)) * t1A + fabsf(a1A));
        vB[1] = 0.5f * ((2.0f - fabsf(a1B)) * t1B + fabsf(a1B));
        vC[1] = 0.5f * ((2.0f - fabsf(a1C)) * t1C + fabsf(a1C));
        #pragma unroll
        for (int j = 0; j < 3; ++j) {
            vA[2 + j] = Lg[I * 5 + 2 + j];
            vB[2 + j] = Lg[(I + 1) * 5 + 2 + j];
            vC[2 + j] = Lg[I2 * 5 + 2 + j];
        }
    }
    float If = (float)I;
    float Cs[5], Ds[5], Csb[5], Dsb[5];
    #pragma unroll
    for (int j = 0; j < 5; ++j) {
        Cs[j]  = fmaf(pos0 - If,       vB[j] - vA[j], vA[j]);
        Ds[j]  = KPOS * (vB[j] - vA[j]);
        Csb[j] = fmaf(pos0 - If - 1.f, vC[j] - vB[j], vB[j]);
        Dsb[j] = KPOS * (vC[j] - vB[j]);
    }

    // own exclusive block-local prefix (coalesced SoA reads)
    float L00 = pref[0 * NCH + t], L01 = pref[1 * NCH + t];
    float L10 = pref[2 * NCH + t], L11 = pref[3 * NCH + t];
    float Lv0 = pref[4 * NCH + t], Lv1 = pref[5 * NCH + t];

    __syncthreads();   // sbs ready

    float bs0 = sbs[0], bs1 = sbs[1];
    float s0v = L00 * bs0 + L01 * bs1 + Lv0;   // y[n0-1]
    float s1v = L10 * bs0 + L11 * bs1 + Lv1;   // y[n0-2]

    const float4* xp = (const float4*)x + (size_t)t * (CS / 4);
    float4*       op = (float4*)out + (size_t)t * (CS / 4);
    #pragma unroll
    for (int j = 0; j < CS / 4; ++j) {
        float4 xv = xp[j];
        float4 yv;
        #pragma unroll
        for (int u = 0; u < 4; ++u) {
            int k = j * 4 + u;
            float xn = (&xv.x)[u];
            bool sB = (k >= kc);
            float kf = (float)k;
            float a1 = fmaf(kf, sB ? Dsb[0] : Ds[0], sB ? Csb[0] : Cs[0]);
            float a2 = fmaf(kf, sB ? Dsb[1] : Ds[1], sB ? Csb[1] : Cs[1]);
            float b0 = fmaf(kf, sB ? Dsb[2] : Ds[2], sB ? Csb[2] : Cs[2]);
            float b1 = fmaf(kf, sB ? Dsb[3] : Ds[3], sB ? Csb[3] : Cs[3]);
            float b2 = fmaf(kf, sB ? Dsb[4] : Ds[4], sB ? Csb[4] : Cs[4]);
            float y = fmaf(-a2, s1v, fmaf(-a1, s0v, xn));
            (&yv.x)[u] = fmaf(b2, s1v, fmaf(b1, s0v, b0 * y));
            s1v = s0v; s0v = y;
        }
        op[j] = yv;
    }
}

extern "C" void kernel_launch(void* const* d_in, const int* in_sizes, int n_in,
                              void* d_out, int out_size, void* d_ws, size_t ws_size,
                              hipStream_t stream) {
    const float* x      = (const float*)d_in[0];   // (B, N) f32
    const float* logits = (const float*)d_in[1];   // (B, F, 5) f32
    float* out = (float*)d_out;                    // (B, N) f32
    float* ws  = (float*)d_ws;

    float* pref = ws + OFF_PREF;
    float* agg  = ws + OFF_AGG;

    phaseA<<<NBLK, TPB, 0, stream>>>(x, logits, pref, agg);
    phaseC<<<NBLK, TPB, 0, stream>>>(x, logits, pref, agg, out);
}